// Round 4
// baseline (136.469 us; speedup 1.0000x reference)
//
#include <hip/hip_runtime.h>
#include <hip/hip_bf16.h>

#define B_   32
#define C_   128
#define L_   4096
#define P_   100
#define NPT  7            // p-tiles of 16 (P padded to 112)
#define Q_   20
#define NBIN 21
#define NCH  (NPT * 4)    // 28 A-frag chunks; chunk = pt*4 + ks
#define CHS  512          // shorts per chunk = 64 lanes * 8 bf16 (1 KB)

typedef short          bf16x8 __attribute__((ext_vector_type(8)));
typedef float          f32x4  __attribute__((ext_vector_type(4)));
typedef unsigned short u16x8  __attribute__((ext_vector_type(8)));

__device__ inline unsigned short f2bf(float f) {
    __hip_bfloat16 h = __float2bfloat16(f);   // RNE
    unsigned short u; __builtin_memcpy(&u, &h, 2);
    return u;
}

__device__ inline bf16x8 pack8(const float* v) {
    unsigned int u[4];
#pragma unroll
    for (int jp = 0; jp < 4; ++jp) {
        __hip_bfloat162 h2 = __float22bfloat162_rn(make_float2(v[2 * jp], v[2 * jp + 1]));
        __builtin_memcpy(&u[jp], &h2, 4);
    }
    bf16x8 r; __builtin_memcpy(&r, u, 16);
    return r;
}

// ---- prep: W (fp32 [P][C]) -> bf16 fragment lane order in d_ws ----
// Wf[chunk][lane][j], chunk=pt*4+ks: value = W[pt*16 + (lane&15)][ks*32 + (lane>>4)*8 + j]
// (rows p>=100 zeroed). Main kernel copies with plain dwordx4 -> conflict-free
// ds_read_b128 fragments. (R3: restored — R1's in-kernel prep cost ~3 us: every
// block re-read 51 KB of W from L2 + cvt on its critical path.)
__global__ void prep_w_kernel(const float* __restrict__ W, unsigned short* __restrict__ Wf) {
    const int t = blockIdx.x * 256 + threadIdx.x;     // 0 .. NCH*64-1
    if (t >= NCH * 64) return;
    const int chunk = t >> 6, lane = t & 63;
    const int pt = chunk >> 2, ks = chunk & 3;
    const int p  = pt * 16 + (lane & 15);
    const int c0 = ks * 32 + (lane >> 4) * 8;
    u16x8 v;
#pragma unroll
    for (int j = 0; j < 8; ++j)
        v[j] = (p < P_) ? f2bf(W[p * C_ + c0 + j]) : (unsigned short)0;
    *(u16x8*)(Wf + (size_t)t * 8) = v;                // 16B coalesced store
}

// ---- main: block = (b, 128-l chunk), 4 waves; wave owns 32 l (2 l-tiles) ----
// D[p][l] = sum_c W[p][c] * X[b][c][l] via mfma_f32_16x16x32_bf16.
//
// R3 change: TWO-PASS l-tile SOFTWARE PIPELINE. Old structure: all 64 X loads
// -> cvt -> one pt-loop using both l-tiles => chip-wide load burst (~11 us,
// compute idle) then compute tail (~7 us, memory idle), additive. New: issue
// all 64 loads, then wait only for the first 32 (compiler emits partial vmcnt),
// cvt + full pt pass over l-tile 0 WHILE l-tile 1's loads are still in flight;
// then cvt + pass over l-tile 1. Cost: afrag ds_reads double (28->56/wave) —
// LDS-pipe cheap vs the load/compute overlap bought.
//
// R2 (kept): swapped MFMA operands -> D row=l(quad*4+r), col=p(nn); one atomic
// instruction touches 16 different hist rows; mn/invd hoisted per pt.
//   algebra: A'[m][k]=X[ks*32+k][l0+lt*16+m], B'[k][n]=W[pt*16+n][ks*32+k]
//   => D'[m][n] = a[b, p=pt*16+n, l=l0+lt*16+m]   (m89-verified C/D mapping)
//
// PHASE ORDER (prior-session R5 post-mortem): __syncthreads drains vmcnt(0),
// so the ONLY pre-epilogue barrier (after W->LDS copy + hist zero) happens
// BEFORE any X load; afterwards each wave streams with no barrier.
//   Histogram: 21 uniform bins, prefix-sum epilogue, exact fp32 atomicAdd
//   (multiples of 2^-12, counts<=4096).
__global__ __launch_bounds__(256, 4)
void radon_mfma4_kernel(const float* __restrict__ X, const unsigned short* __restrict__ Wf,
                        const float* __restrict__ minv, const float* __restrict__ maxv,
                        float* __restrict__ out) {
    __shared__ unsigned short Wlds[NCH * CHS];   // 28.0 KB
    __shared__ int   hist[P_ * NBIN];            // 8.4 KB
    __shared__ float mn_s[P_], invd_s[P_];       // 0.8 KB

    const int tid  = threadIdx.x;
    const int b    = blockIdx.y;
    const int lblk = blockIdx.x;       // 0..31
    const int wave = tid >> 6;
    const int lane = tid & 63;
    const int quad = lane >> 4;
    const int nn   = lane & 15;

    // ---- Phase A: Wf -> LDS (plain dwordx4 copy), thresholds, hist zero, barrier.
    {
        const int4* src = (const int4*)Wf;
        int4* dst = (int4*)Wlds;
#pragma unroll
        for (int k = 0; k < NCH * 64 / 256; ++k)     // 7 iters, L2-resident
            dst[tid + k * 256] = src[tid + k * 256];
    }
    for (int i = tid; i < P_; i += 256) {
        const float mn = minv[i];
        mn_s[i]   = mn;
        invd_s[i] = (float)NBIN / (maxv[i] - mn);
    }
    for (int i = tid; i < P_ * NBIN; i += 256) hist[i] = 0;
    __syncthreads();   // the ONLY barrier before the epilogue

    // ---- Phase B: issue ALL 64 X loads up front (both l-tiles).
    const int l0 = lblk * 128 + wave * 32;
    const float* Xb = X + (size_t)b * C_ * L_ + l0 + nn;
    float xv0[4][8], xv1[4][8];
#pragma unroll
    for (int ks = 0; ks < 4; ++ks)
#pragma unroll
        for (int j = 0; j < 8; ++j)
            xv0[ks][j] = Xb[(size_t)(ks * 32 + quad * 8 + j) * L_];
#pragma unroll
    for (int ks = 0; ks < 4; ++ks)
#pragma unroll
        for (int j = 0; j < 8; ++j)
            xv1[ks][j] = Xb[(size_t)(ks * 32 + quad * 8 + j) * L_ + 16];

    // ---- per-pass pt-loop: 4 afrag ds_read_b128 + 4 MFMA + bucket ----
    auto run_pass = [&](const bf16x8* bfr) {
#pragma unroll 2
        for (int pt = 0; pt < NPT; ++pt) {
            bf16x8 a0 = *(const bf16x8*)(&Wlds[((pt * 4 + 0) * 64 + lane) * 8]);
            bf16x8 a1 = *(const bf16x8*)(&Wlds[((pt * 4 + 1) * 64 + lane) * 8]);
            bf16x8 a2 = *(const bf16x8*)(&Wlds[((pt * 4 + 2) * 64 + lane) * 8]);
            bf16x8 a3 = *(const bf16x8*)(&Wlds[((pt * 4 + 3) * 64 + lane) * 8]);
            f32x4 acc = {0.f, 0.f, 0.f, 0.f};
            // swapped operands: D row = l (quad*4+r), col = p (nn)
            acc = __builtin_amdgcn_mfma_f32_16x16x32_bf16(bfr[0], a0, acc, 0, 0, 0);
            acc = __builtin_amdgcn_mfma_f32_16x16x32_bf16(bfr[1], a1, acc, 0, 0, 0);
            acc = __builtin_amdgcn_mfma_f32_16x16x32_bf16(bfr[2], a2, acc, 0, 0, 0);
            acc = __builtin_amdgcn_mfma_f32_16x16x32_bf16(bfr[3], a3, acc, 0, 0, 0);
            const int p = pt * 16 + nn;      // per-thread constant within pt
            if (p < P_) {
                const float mn = mn_s[p], invd = invd_s[p];
#pragma unroll
                for (int r = 0; r < 4; ++r) {
                    const float t = (acc[r] - mn) * invd;
                    int k = 0;
                    if (t > 0.f) { const int ki = (int)t; k = (ki > 20) ? 20 : ki; }
                    atomicAdd(&hist[p * NBIN + k], 1);
                }
            }
        }
    };

    // ---- Pass A: l-tile 0 (waits only on first 32 loads; xv1 still in flight)
    bf16x8 bfrag0[4];
#pragma unroll
    for (int ks = 0; ks < 4; ++ks) bfrag0[ks] = pack8(xv0[ks]);
    run_pass(bfrag0);

    // ---- Pass B: l-tile 1
    bf16x8 bfrag1[4];
#pragma unroll
    for (int ks = 0; ks < 4; ++ks) bfrag1[ks] = pack8(xv1[ks]);
    run_pass(bfrag1);

    __syncthreads();

    // ---- Phase D: prefix-sum histogram -> exact fp32 atomic accumulation
    for (int i = tid; i < P_ * Q_; i += 256) {
        const int p  = i / Q_;
        const int qi = i - p * Q_;
        int s = 0;
        for (int k = 0; k <= qi; ++k) s += hist[p * NBIN + k];
        atomicAdd(&out[((size_t)b * P_ + p) * Q_ + qi], (float)s * (1.0f / (float)L_));
    }
}

extern "C" void kernel_launch(void* const* d_in, const int* in_sizes, int n_in,
                              void* d_out, int out_size, void* d_ws, size_t ws_size,
                              hipStream_t stream) {
    const float* X  = (const float*)d_in[0];
    const float* W  = (const float*)d_in[1];
    const float* mn = (const float*)d_in[2];
    const float* mx = (const float*)d_in[3];
    float* out = (float*)d_out;
    unsigned short* Wf = (unsigned short*)d_ws;   // needs NCH*64*16 = 28672 bytes

    hipMemsetAsync(out, 0, (size_t)out_size * sizeof(float), stream);
    prep_w_kernel<<<NCH * 64 / 256, 256, 0, stream>>>(W, Wf);

    dim3 grid(L_ / 128, B_);
    radon_mfma4_kernel<<<grid, dim3(256), 0, stream>>>(X, Wf, mn, mx, out);
}

// Round 5
// 104.930 us; speedup vs baseline: 1.3006x; 1.3006x over previous
//
#include <hip/hip_runtime.h>
#include <hip/hip_bf16.h>

#define B_    32
#define C_    128
#define L_    4096
#define P_    100
#define NPT   7            // p-tiles of 16 (P padded to 112)
#define Q_    20
#define NBIN  21
#define NCH   (NPT * 4)    // 28 A-frag chunks; chunk = pt*4 + ks
#define CHS   512          // shorts per chunk = 64 lanes * 8 bf16 (1 KB)
#define TPB   1024         // R4: 16-wave blocks (4 old blocks merged)
#define LSPAN 512          // l-columns per block

typedef short          bf16x8 __attribute__((ext_vector_type(8)));
typedef float          f32x4  __attribute__((ext_vector_type(4)));
typedef unsigned short u16x8  __attribute__((ext_vector_type(8)));

__device__ inline unsigned short f2bf(float f) {
    __hip_bfloat16 h = __float2bfloat16(f);   // RNE
    unsigned short u; __builtin_memcpy(&u, &h, 2);
    return u;
}

// ---- prep: W (fp32 [P][C]) -> bf16 fragment lane order in d_ws ----
// Wf[chunk][lane][j], chunk=pt*4+ks: value = W[pt*16 + (lane&15)][ks*32 + (lane>>4)*8 + j]
// (rows p>=100 zeroed). Main kernel copies with plain dwordx4 -> conflict-free
// ds_read_b128 fragments.
__global__ void prep_w_kernel(const float* __restrict__ W, unsigned short* __restrict__ Wf) {
    const int t = blockIdx.x * 256 + threadIdx.x;     // 0 .. NCH*64-1
    if (t >= NCH * 64) return;
    const int chunk = t >> 6, lane = t & 63;
    const int pt = chunk >> 2, ks = chunk & 3;
    const int p  = pt * 16 + (lane & 15);
    const int c0 = ks * 32 + (lane >> 4) * 8;
    u16x8 v;
#pragma unroll
    for (int j = 0; j < 8; ++j)
        v[j] = (p < P_) ? f2bf(W[p * C_ + c0 + j]) : (unsigned short)0;
    *(u16x8*)(Wf + (size_t)t * 8) = v;                // 16B coalesced store
}

// ---- main: block = (b, 512-l span), 16 waves; wave owns 32 l (2 l-tiles) ----
// D[p][l] = sum_c W[p][c] * X[b][c][l] via mfma_f32_16x16x32_bf16.
//
// R4 change: MERGE 4 BLOCKS INTO ONE 1024-THREAD BLOCK (grid 8x32, was 32x32).
// R3 post-mortem: passing xv/bfrag arrays through pointer params put them in
// SCRATCH (VGPR=64 + 54 MB spill writes, radon 53 us) -> all inner code here is
// the verified R0/R2 INLINE form, static indices only. The merge cuts the costs
// that scale with block count: epilogue device-atomics 2.05M -> 512K lane-ops
// (each out address now hit by 8 blocks, not 32), Phase-A W-copy L2 traffic
// 28.7 MB -> 7.2 MB, 4x fewer threshold loads / hist zeros. Per-CU residency
// unchanged: 1 block = 16 waves (was 4 blocks x 4 waves); LDS 37.9 KB fits.
//
// R2 (kept): swapped MFMA operands -> D row=l(quad*4+r), col=p(nn); one atomic
// instruction touches 16 different hist rows; mn/invd hoisted per pt.
//   algebra: A'[m][k]=X[ks*32+k][l0+lt*16+m], B'[k][n]=W[pt*16+n][ks*32+k]
//   => D'[m][n] = a[b, p=pt*16+n, l=l0+lt*16+m]   (m89-verified C/D mapping)
//
// PHASE ORDER (prior-session post-mortem): __syncthreads drains vmcnt(0), so
// the ONLY pre-epilogue barrier (after W->LDS copy + hist zero) happens BEFORE
// any X load; afterwards each wave streams loads -> cvt -> ds_read -> MFMA ->
// bucket with no barrier, so one wave's compute overlaps others' loads.
//   Histogram: 21 uniform bins, prefix-sum epilogue, exact fp32 atomicAdd
//   (counts <= 512 per bin, multiples of 2^-12, sums <= 1 -> exact in fp32).
__global__ __launch_bounds__(TPB, 4)
void radon_mfma5_kernel(const float* __restrict__ X, const unsigned short* __restrict__ Wf,
                        const float* __restrict__ minv, const float* __restrict__ maxv,
                        float* __restrict__ out) {
    __shared__ unsigned short Wlds[NCH * CHS];   // 28.0 KB
    __shared__ int   hist[P_ * NBIN];            // 8.4 KB
    __shared__ float mn_s[P_], invd_s[P_];       // 0.8 KB

    const int tid  = threadIdx.x;
    const int b    = blockIdx.y;
    const int lblk = blockIdx.x;       // 0..7
    const int wave = tid >> 6;         // 0..15
    const int lane = tid & 63;
    const int quad = lane >> 4;
    const int nn   = lane & 15;

    // ---- Phase A: Wf -> LDS (plain dwordx4 copy), thresholds, hist zero, barrier.
    {
        const int4* src = (const int4*)Wf;
        int4* dst = (int4*)Wlds;
        for (int k = tid; k < NCH * 64; k += TPB)    // 1792 int4, L2-resident
            dst[k] = src[k];
    }
    for (int i = tid; i < P_; i += TPB) {
        const float mn = minv[i];
        mn_s[i]   = mn;
        invd_s[i] = (float)NBIN / (maxv[i] - mn);
    }
    for (int i = tid; i < P_ * NBIN; i += TPB) hist[i] = 0;
    __syncthreads();   // the ONLY barrier before the epilogue

    // ---- Phase B: X loads + packed cvt (compiler interleaves, fine-grained vmcnt)
    const int l0 = lblk * LSPAN + wave * 32;
    const float* Xb = X + (size_t)b * C_ * L_;
    float xv[2][4][8];
#pragma unroll
    for (int lt = 0; lt < 2; ++lt)
#pragma unroll
        for (int ks = 0; ks < 4; ++ks)
#pragma unroll
            for (int j = 0; j < 8; ++j)
                xv[lt][ks][j] = Xb[(size_t)(ks * 32 + quad * 8 + j) * L_ + l0 + lt * 16 + nn];

    bf16x8 bfrag[2][4];
#pragma unroll
    for (int lt = 0; lt < 2; ++lt)
#pragma unroll
        for (int ks = 0; ks < 4; ++ks) {
            unsigned int u[4];
#pragma unroll
            for (int jp = 0; jp < 4; ++jp) {
                __hip_bfloat162 h2 = __float22bfloat162_rn(
                    make_float2(xv[lt][ks][2 * jp], xv[lt][ks][2 * jp + 1]));
                __builtin_memcpy(&u[jp], &h2, 4);
            }
            __builtin_memcpy(&bfrag[lt][ks], u, 16);
        }

    // ---- Phase C: 7 p-tiles, no barrier: ds_read W-frags + 8 MFMAs + bucket
    // p = pt*16 + nn is PER-THREAD CONSTANT within a pt iteration.
    for (int pt = 0; pt < NPT; ++pt) {
        bf16x8 afrag[4];
#pragma unroll
        for (int ks = 0; ks < 4; ++ks)
            afrag[ks] = *(const bf16x8*)(&Wlds[((pt * 4 + ks) * 64 + lane) * 8]);

        f32x4 acc0 = {0.f, 0.f, 0.f, 0.f};
        f32x4 acc1 = {0.f, 0.f, 0.f, 0.f};
#pragma unroll
        for (int ks = 0; ks < 4; ++ks) {
            // swapped operands: D row = l (quad*4+r), col = p (nn)
            acc0 = __builtin_amdgcn_mfma_f32_16x16x32_bf16(bfrag[0][ks], afrag[ks], acc0, 0, 0, 0);
            acc1 = __builtin_amdgcn_mfma_f32_16x16x32_bf16(bfrag[1][ks], afrag[ks], acc1, 0, 0, 0);
        }

        const int p = pt * 16 + nn;
        if (p < P_) {
            const float mn = mn_s[p], invd = invd_s[p];
            int* __restrict__ hrow = &hist[p * NBIN];
#pragma unroll
            for (int r = 0; r < 4; ++r) {
                {
                    const float t = (acc0[r] - mn) * invd;
                    int k = 0;
                    if (t > 0.f) { const int ki = (int)t; k = (ki > 20) ? 20 : ki; }
                    atomicAdd(&hrow[k], 1);
                }
                {
                    const float t = (acc1[r] - mn) * invd;
                    int k = 0;
                    if (t > 0.f) { const int ki = (int)t; k = (ki > 20) ? 20 : ki; }
                    atomicAdd(&hrow[k], 1);
                }
            }
        }
    }
    __syncthreads();

    // ---- Phase D: prefix-sum histogram -> exact fp32 atomic accumulation
    for (int i = tid; i < P_ * Q_; i += TPB) {
        const int p  = i / Q_;
        const int qi = i - p * Q_;
        int s = 0;
        for (int k = 0; k <= qi; ++k) s += hist[p * NBIN + k];
        atomicAdd(&out[((size_t)b * P_ + p) * Q_ + qi], (float)s * (1.0f / (float)L_));
    }
}

extern "C" void kernel_launch(void* const* d_in, const int* in_sizes, int n_in,
                              void* d_out, int out_size, void* d_ws, size_t ws_size,
                              hipStream_t stream) {
    const float* X  = (const float*)d_in[0];
    const float* W  = (const float*)d_in[1];
    const float* mn = (const float*)d_in[2];
    const float* mx = (const float*)d_in[3];
    float* out = (float*)d_out;
    unsigned short* Wf = (unsigned short*)d_ws;   // needs NCH*64*16 = 28672 bytes

    hipMemsetAsync(out, 0, (size_t)out_size * sizeof(float), stream);
    prep_w_kernel<<<NCH * 64 / 256, 256, 0, stream>>>(W, Wf);

    dim3 grid(L_ / LSPAN, B_);
    radon_mfma5_kernel<<<grid, dim3(TPB), 0, stream>>>(X, Wf, mn, mx, out);
}